// Round 5
// baseline (149.872 us; speedup 1.0000x reference)
//
#include <hip/hip_runtime.h>
#include <stdint.h>

#define BB 4
#define NN 2048
#define FIN 256
#define FOUT 128
#define NH 4
#define NEG_SLOPE 0.2f

typedef short bf16x8 __attribute__((ext_vector_type(8)));
typedef unsigned short u16x8 __attribute__((ext_vector_type(8)));
typedef float f32x4 __attribute__((ext_vector_type(4)));
typedef unsigned long long u64;

__device__ inline float b2f(unsigned short u) {
    union { unsigned int i; float f; } x; x.i = ((unsigned int)u) << 16; return x.f;
}
__device__ inline unsigned short f2b(float f) {   // fp32 -> bf16 RNE
    union { float f; unsigned int i; } x; x.f = f;
    unsigned int r = x.i + 0x7fffu + ((x.i >> 16) & 1u);
    return (unsigned short)(r >> 16);
}
__device__ inline unsigned short f2b_fast(float f) {  // round-half-up (f >= 0 here)
    union { float f; unsigned int i; } x; x.f = f;
    return (unsigned short)((x.i + 0x8000u) >> 16);
}

// ---------------------------------------------------------------------------
// k0_prep (fused): blocks [0,128): W fp32 -> bf16 hi/lo split.
// blocks [128,128+NN): adj row -> 32 u64 bitmask words.
// NOTE: no cross-block fences anywhere — R2 showed device-scope __threadfence
// costs ~120 µs aggregate on this chip. Kernel boundaries are the cheap
// device-scope ordering primitive here.
// ---------------------------------------------------------------------------
__global__ __launch_bounds__(256) void k0_prep(const float* __restrict__ Ww,
                                               unsigned short* __restrict__ Whi,
                                               unsigned short* __restrict__ Wlo,
                                               const int* __restrict__ adj,
                                               u64* __restrict__ mask) {
    int bid = blockIdx.x;
    if (bid < 128) {
        int idx = bid * 256 + threadIdx.x;   // 32768 elems
        float v = Ww[idx];
        unsigned short hb = f2b(v);
        Whi[idx] = hb;
        Wlo[idx] = f2b(v - b2f(hb));
    } else {
        int row = bid - 128;
        int wave = threadIdx.x >> 6, lane = threadIdx.x & 63;
        #pragma unroll
        for (int it = 0; it < 8; ++it) {
            int w = it * 4 + wave;
            int j = w * 64 + lane;
            u64 m = __ballot(adj[(size_t)row * NN + j] != 0);
            if (lane == 0) mask[row * 32 + w] = m;
        }
    }
}

// ---------------------------------------------------------------------------
// K1 (MFMA): Wh[16 rows][128 o] = h_tile @ W^T + b, split-bf16 (hh+hl+lh).
// Epilogue: WhT bf16 [b][o][n]; exp tables (fp32):
//   ELpair[b*4+h][i]   = (exp(eL), exp(0.2 eL)) fp32x2
//   ERf  [b][j][h]     = (exp(eR), exp(0.2 eR)) fp32x2
// ---------------------------------------------------------------------------
__global__ __launch_bounds__(256) void k1_wh(
    const float* __restrict__ h, const unsigned short* __restrict__ Whi,
    const unsigned short* __restrict__ Wlo, const float* __restrict__ Wb,
    const float* __restrict__ attw, unsigned short* __restrict__ WhT,
    float2* __restrict__ ELpair, float2* __restrict__ ERf) {
    __shared__ unsigned short Ahi[16][264];
    __shared__ unsigned short Alo[16][264];
    __shared__ float whs[16][132];
    int t = threadIdx.x;
    int b = blockIdx.x >> 7;
    int n0 = (blockIdx.x & 127) * 16;
    {
        int r = t >> 4, c = (t & 15) * 16;
        const float* hp = h + ((size_t)(b * NN + n0 + r)) * FIN + c;
        u16x8 hi0, hi1, lo0, lo1;
        #pragma unroll
        for (int q = 0; q < 4; ++q) {
            float4 v = *(const float4*)(hp + q * 4);
            float vv[4] = {v.x, v.y, v.z, v.w};
            #pragma unroll
            for (int e = 0; e < 4; ++e) {
                int idx = q * 4 + e;
                unsigned short hb = f2b(vv[e]);
                unsigned short lb = f2b(vv[e] - b2f(hb));
                if (idx < 8) { hi0[idx] = (short)hb; lo0[idx] = (short)lb; }
                else         { hi1[idx - 8] = (short)hb; lo1[idx - 8] = (short)lb; }
            }
        }
        *(u16x8*)&Ahi[r][c] = *(u16x8*)&hi0;
        *(u16x8*)&Ahi[r][c + 8] = *(u16x8*)&hi1;
        *(u16x8*)&Alo[r][c] = *(u16x8*)&lo0;
        *(u16x8*)&Alo[r][c + 8] = *(u16x8*)&lo1;
    }
    __syncthreads();
    int lane = t & 63, wv = t >> 6;
    int m = lane & 15, quad = lane >> 4;
    int o0 = wv * 32;
    f32x4 acc0 = {0.f, 0.f, 0.f, 0.f}, acc1 = {0.f, 0.f, 0.f, 0.f};
    const unsigned short* wh0 = Whi + (size_t)(o0 + m) * FIN;
    const unsigned short* wl0 = Wlo + (size_t)(o0 + m) * FIN;
    const unsigned short* wh1 = Whi + (size_t)(o0 + 16 + m) * FIN;
    const unsigned short* wl1 = Wlo + (size_t)(o0 + 16 + m) * FIN;
    #pragma unroll
    for (int ks = 0; ks < 8; ++ks) {
        int ko = ks * 32 + quad * 8;
        bf16x8 ahi = *(bf16x8*)&Ahi[m][ko];
        bf16x8 alo = *(bf16x8*)&Alo[m][ko];
        bf16x8 bh0 = *(const bf16x8*)(wh0 + ko);
        bf16x8 bl0 = *(const bf16x8*)(wl0 + ko);
        bf16x8 bh1 = *(const bf16x8*)(wh1 + ko);
        bf16x8 bl1 = *(const bf16x8*)(wl1 + ko);
        acc0 = __builtin_amdgcn_mfma_f32_16x16x32_bf16(ahi, bh0, acc0, 0, 0, 0);
        acc0 = __builtin_amdgcn_mfma_f32_16x16x32_bf16(ahi, bl0, acc0, 0, 0, 0);
        acc0 = __builtin_amdgcn_mfma_f32_16x16x32_bf16(alo, bh0, acc0, 0, 0, 0);
        acc1 = __builtin_amdgcn_mfma_f32_16x16x32_bf16(ahi, bh1, acc1, 0, 0, 0);
        acc1 = __builtin_amdgcn_mfma_f32_16x16x32_bf16(ahi, bl1, acc1, 0, 0, 0);
        acc1 = __builtin_amdgcn_mfma_f32_16x16x32_bf16(alo, bh1, acc1, 0, 0, 0);
    }
    float bias0 = Wb[o0 + m], bias1 = Wb[o0 + 16 + m];
    #pragma unroll
    for (int reg = 0; reg < 4; ++reg) {
        int row = quad * 4 + reg;
        whs[row][o0 + m] = acc0[reg] + bias0;
        whs[row][o0 + 16 + m] = acc1[reg] + bias1;
    }
    __syncthreads();
    {   // WhT writer: 2 threads per o, 8 n each
        int o = t >> 1, half = t & 1;
        u16x8 v8;
        #pragma unroll
        for (int r = 0; r < 8; ++r) v8[r] = (short)f2b(whs[half * 8 + r][o]);
        *(u16x8*)(WhT + (size_t)(b * FOUT + o) * NN + n0 + half * 8) = v8;
    }
    {   // e-dots + exp tables
        int outi = t >> 1, half = t & 1;
        int i = outi >> 3, d = outi & 7, hh = d & 3, side = d >> 2;
        const float* arow = attw + hh * (2 * FOUT) + side * FOUT + half * 64;
        float s = 0.f;
        #pragma unroll 8
        for (int k = 0; k < 64; ++k) s = fmaf(whs[i][half * 64 + k], arow[k], s);
        s += __shfl_xor(s, 1);
        if (half == 0) {
            float p = __expf(s), n = __expf(NEG_SLOPE * s);
            if (side == 0) {
                ELpair[(size_t)(b * NH + hh) * NN + n0 + i] = make_float2(p, n);
            } else {
                ERf[((size_t)b * NN + n0 + i) * NH + hh] = make_float2(p, n);
            }
        }
    }
}

// ---------------------------------------------------------------------------
// K2 (fully fused): per block = (b, 16 i-rows) x ALL 2048 j.
//   phase 1: denominators S_h[i] (strip-parallel sweep, LDS reduce)
//   phase 2: 8 chunks of 256 j: build combined-head bf16 weight tile in LDS,
//            MFMA-accumulate against WhT. Epilogue: relu(acc) -> out.
// Replaces kstat_t + k2b + k3: no sPartT, no P, 2 fewer launches, no fences.
// Grid (128, 4) = 512 blocks x 512 thr = 2 blocks/CU in one generation.
// ---------------------------------------------------------------------------
__global__ __launch_bounds__(512, 4) void k2_fused(
    const unsigned short* __restrict__ WhT, const float2* __restrict__ ERf,
    const float2* __restrict__ ELpair, const u64* __restrict__ mask,
    float* __restrict__ out) {
    __shared__ unsigned short wt[16][264];   // 8.4 KB bf16 weight tile (256 j)
    __shared__ u64 mws[16][32];              // 4 KB: full-row mask words
    __shared__ float part[32][16][NH];       // 8 KB: phase-1 partials
    __shared__ float elsc_s[16][8];          // 512 B
    int t = threadIdx.x;
    int b = blockIdx.y, i0 = blockIdx.x * 16;
    int lane = t & 63, wv = t >> 6;
    int m = lane & 15, quad = lane >> 4;

    {   // stage all mask words for 16 rows: 512 words, 1 per thread
        int r = t >> 5, w = t & 31;
        mws[r][w] = mask[(size_t)(i0 + r) * 32 + w];
    }
    __syncthreads();

    // ---- phase 1: S_h[i] = sum_j bit(i,j)*max(elp*erp, eln*ern)
    {   // thread: i = t&15, strip = t>>4 (32 strips of 64 j)
        int i = t & 15, strip = t >> 4;
        float elp[NH], eln[NH], acc[NH];
        #pragma unroll
        for (int hh = 0; hh < NH; ++hh) {
            float2 e2 = ELpair[(size_t)(b * NH + hh) * NN + i0 + i];
            elp[hh] = e2.x; eln[hh] = e2.y; acc[hh] = 0.f;
        }
        u64 mw = mws[i][strip];
        const float4* erb = (const float4*)(ERf + ((size_t)b * NN + strip * 64) * NH);
        #pragma unroll 8
        for (int jj = 0; jj < 64; ++jj) {
            float4 e0 = erb[jj * 2];
            float4 e1 = erb[jj * 2 + 1];
            bool bit = (mw >> jj) & 1ull;
            float m0 = fmaxf(elp[0] * e0.x, eln[0] * e0.y);
            float m1 = fmaxf(elp[1] * e0.z, eln[1] * e0.w);
            float m2 = fmaxf(elp[2] * e1.x, eln[2] * e1.y);
            float m3 = fmaxf(elp[3] * e1.z, eln[3] * e1.w);
            acc[0] += bit ? m0 : 0.f;
            acc[1] += bit ? m1 : 0.f;
            acc[2] += bit ? m2 : 0.f;
            acc[3] += bit ? m3 : 0.f;
        }
        #pragma unroll
        for (int hh = 0; hh < NH; ++hh) part[strip][i][hh] = acc[hh];
    }
    __syncthreads();
    if (t < 64) {   // reduce 32 strips; fold 1/(4S) into EL pair
        int i = t >> 2, hh = t & 3;
        float s = 0.f;
        #pragma unroll
        for (int st = 0; st < 32; ++st) s += part[st][i][hh];
        float iv = (s > 0.f) ? 0.25f / s : 0.f;
        float2 e2 = ELpair[(size_t)(b * NH + hh) * NN + i0 + i];
        elsc_s[i][hh * 2]     = e2.x * iv;
        elsc_s[i][hh * 2 + 1] = e2.y * iv;
    }

    // ---- phase 2: full-j accumulation, 8 chunks of 256 j
    const unsigned short* bp = WhT + (size_t)(b * FOUT + wv * 16 + m) * NN;
    f32x4 acc = {0.f, 0.f, 0.f, 0.f};
    for (int ch = 0; ch < 8; ++ch) {
        int j0 = ch * 256;
        __syncthreads();                      // elsc/wt ready-to-overwrite
        bf16x8 bfr[8];                        // prefetch B operands (L2)
        #pragma unroll
        for (int ks = 0; ks < 8; ++ks)
            bfr[ks] = *(const bf16x8*)(bp + j0 + ks * 32 + quad * 8);
        float erp[4][4], ern[4][4];
        #pragma unroll
        for (int q = 0; q < 4; ++q) {
            int jg = j0 + q * 64 + lane;
            const float4* ef = (const float4*)(ERf + ((size_t)b * NN + jg) * NH);
            float4 e0 = ef[0], e1 = ef[1];
            erp[q][0] = e0.x; ern[q][0] = e0.y;
            erp[q][1] = e0.z; ern[q][1] = e0.w;
            erp[q][2] = e1.x; ern[q][2] = e1.y;
            erp[q][3] = e1.z; ern[q][3] = e1.w;
        }
        #pragma unroll
        for (int r = 0; r < 2; ++r) {         // each wave builds 2 rows
            int ir = wv * 2 + r;
            float4 c0 = *(float4*)&elsc_s[ir][0];
            float4 c1 = *(float4*)&elsc_s[ir][4];
            #pragma unroll
            for (int q = 0; q < 4; ++q) {
                float p = fmaxf(c0.x * erp[q][0], c0.y * ern[q][0]);
                p += fmaxf(c0.z * erp[q][1], c0.w * ern[q][1]);
                p += fmaxf(c1.x * erp[q][2], c1.y * ern[q][2]);
                p += fmaxf(c1.z * erp[q][3], c1.w * ern[q][3]);
                wt[ir][q * 64 + lane] =
                    ((mws[ir][ch * 4 + q] >> lane) & 1ull) ? f2b_fast(p) : 0;
            }
        }
        __syncthreads();
        #pragma unroll
        for (int ks = 0; ks < 8; ++ks) {
            bf16x8 a = *(bf16x8*)&wt[m][ks * 32 + quad * 8];
            acc = __builtin_amdgcn_mfma_f32_16x16x32_bf16(a, bfr[ks], acc, 0, 0, 0);
        }
    }
    // ---- epilogue: relu + direct store (no P partials)
    #pragma unroll
    for (int reg = 0; reg < 4; ++reg) {
        int row = quad * 4 + reg;
        out[((size_t)b * NN + i0 + row) * FOUT + wv * 16 + m] =
            fmaxf(acc[reg], 0.f);
    }
}

extern "C" void kernel_launch(void* const* d_in, const int* in_sizes, int n_in,
                              void* d_out, int out_size, void* d_ws, size_t ws_size,
                              hipStream_t stream) {
    const float* h    = (const float*)d_in[0];
    const int* adj    = (const int*)d_in[1];
    const float* Ww   = (const float*)d_in[2];
    const float* Wb   = (const float*)d_in[3];
    const float* attw = (const float*)d_in[4];
    float* out = (float*)d_out;
    char* ws = (char*)d_ws;
    // workspace layout (~3.2 MB)
    unsigned short* Whi = (unsigned short*)(ws);                 // 64 KB
    unsigned short* Wlo = (unsigned short*)(ws + 65536);         // 64 KB
    unsigned short* WhT = (unsigned short*)(ws + 131072);        // 2 MB [b][o][n] bf16
    float2*       ELpair = (float2*)(ws + 2228224);              // 256 KB [bh][i]
    float2*       ERf    = (float2*)(ws + 2490368);              // 256 KB [b][j][h] f32 pair
    u64*          mask   = (u64*)(ws + 2752512);                 // 512 KB

    k0_prep<<<dim3(128 + NN), dim3(256), 0, stream>>>(Ww, Whi, Wlo, adj, mask);
    k1_wh<<<dim3(BB * NN / 16), dim3(256), 0, stream>>>(h, Whi, Wlo, Wb, attw,
                                                        WhT, ELpair, ERf);
    k2_fused<<<dim3(NN / 16, BB), dim3(512), 0, stream>>>(WhT, ERf, ELpair,
                                                          mask, out);
}

// Round 10
// 144.815 us; speedup vs baseline: 1.0349x; 1.0349x over previous
//
#include <hip/hip_runtime.h>
#include <stdint.h>

#define BB 4
#define NN 2048
#define FIN 256
#define FOUT 128
#define NH 4
#define NEG_SLOPE 0.2f

typedef short bf16x8 __attribute__((ext_vector_type(8)));
typedef unsigned short u16x8 __attribute__((ext_vector_type(8)));
typedef float f32x4 __attribute__((ext_vector_type(4)));
typedef unsigned long long u64;

__device__ inline float b2f(unsigned short u) {
    union { unsigned int i; float f; } x; x.i = ((unsigned int)u) << 16; return x.f;
}
__device__ inline unsigned short f2b(float f) {   // fp32 -> bf16 RNE
    union { float f; unsigned int i; } x; x.f = f;
    unsigned int r = x.i + 0x7fffu + ((x.i >> 16) & 1u);
    return (unsigned short)(r >> 16);
}
__device__ inline unsigned short f2b_fast(float f) {  // round-half-up (f >= 0 here)
    union { float f; unsigned int i; } x; x.f = f;
    return (unsigned short)((x.i + 0x8000u) >> 16);
}

// ---------------------------------------------------------------------------
// NOTE (timing model, R5): the harness's 256 MB workspace poison-fill (~43 µs)
// runs INSIDE the timed window each iteration. Controllable budget = dur - 43.
// NOTE (R2): no cross-block fences — device-scope __threadfence cost ~120 µs.
// ---------------------------------------------------------------------------

// ---------------------------------------------------------------------------
// k0_prep (fused): blocks [0,128): W fp32 -> bf16 hi/lo split.
// blocks [128,128+NN): adj row -> 32 u64 bitmask words.
// ---------------------------------------------------------------------------
__global__ __launch_bounds__(256) void k0_prep(const float* __restrict__ Ww,
                                               unsigned short* __restrict__ Whi,
                                               unsigned short* __restrict__ Wlo,
                                               const int* __restrict__ adj,
                                               u64* __restrict__ mask) {
    int bid = blockIdx.x;
    if (bid < 128) {
        int idx = bid * 256 + threadIdx.x;   // 32768 elems
        float v = Ww[idx];
        unsigned short hb = f2b(v);
        Whi[idx] = hb;
        Wlo[idx] = f2b(v - b2f(hb));
    } else {
        int row = bid - 128;
        int wave = threadIdx.x >> 6, lane = threadIdx.x & 63;
        #pragma unroll
        for (int it = 0; it < 8; ++it) {
            int w = it * 4 + wave;
            int j = w * 64 + lane;
            u64 m = __ballot(adj[(size_t)row * NN + j] != 0);
            if (lane == 0) mask[row * 32 + w] = m;
        }
    }
}

// ---------------------------------------------------------------------------
// K1 (MFMA): Wh[16 rows][128 o] = h_tile @ W^T + b, split-bf16 (hh+hl+lh).
// Epilogue: WhT bf16 [b][o][n]; exp tables (fp32):
//   ELpair[b*4+h][i]   = (exp(eL), exp(0.2 eL)) fp32x2
//   ERf  [b][j][h]     = (exp(eR), exp(0.2 eR)) fp32x2
// ---------------------------------------------------------------------------
__global__ __launch_bounds__(256) void k1_wh(
    const float* __restrict__ h, const unsigned short* __restrict__ Whi,
    const unsigned short* __restrict__ Wlo, const float* __restrict__ Wb,
    const float* __restrict__ attw, unsigned short* __restrict__ WhT,
    float2* __restrict__ ELpair, float2* __restrict__ ERf) {
    __shared__ unsigned short Ahi[16][264];
    __shared__ unsigned short Alo[16][264];
    __shared__ float whs[16][132];
    int t = threadIdx.x;
    int b = blockIdx.x >> 7;
    int n0 = (blockIdx.x & 127) * 16;
    {
        int r = t >> 4, c = (t & 15) * 16;
        const float* hp = h + ((size_t)(b * NN + n0 + r)) * FIN + c;
        u16x8 hi0, hi1, lo0, lo1;
        #pragma unroll
        for (int q = 0; q < 4; ++q) {
            float4 v = *(const float4*)(hp + q * 4);
            float vv[4] = {v.x, v.y, v.z, v.w};
            #pragma unroll
            for (int e = 0; e < 4; ++e) {
                int idx = q * 4 + e;
                unsigned short hb = f2b(vv[e]);
                unsigned short lb = f2b(vv[e] - b2f(hb));
                if (idx < 8) { hi0[idx] = (short)hb; lo0[idx] = (short)lb; }
                else         { hi1[idx - 8] = (short)hb; lo1[idx - 8] = (short)lb; }
            }
        }
        *(u16x8*)&Ahi[r][c] = *(u16x8*)&hi0;
        *(u16x8*)&Ahi[r][c + 8] = *(u16x8*)&hi1;
        *(u16x8*)&Alo[r][c] = *(u16x8*)&lo0;
        *(u16x8*)&Alo[r][c + 8] = *(u16x8*)&lo1;
    }
    __syncthreads();
    int lane = t & 63, wv = t >> 6;
    int m = lane & 15, quad = lane >> 4;
    int o0 = wv * 32;
    f32x4 acc0 = {0.f, 0.f, 0.f, 0.f}, acc1 = {0.f, 0.f, 0.f, 0.f};
    const unsigned short* wh0 = Whi + (size_t)(o0 + m) * FIN;
    const unsigned short* wl0 = Wlo + (size_t)(o0 + m) * FIN;
    const unsigned short* wh1 = Whi + (size_t)(o0 + 16 + m) * FIN;
    const unsigned short* wl1 = Wlo + (size_t)(o0 + 16 + m) * FIN;
    #pragma unroll
    for (int ks = 0; ks < 8; ++ks) {
        int ko = ks * 32 + quad * 8;
        bf16x8 ahi = *(bf16x8*)&Ahi[m][ko];
        bf16x8 alo = *(bf16x8*)&Alo[m][ko];
        bf16x8 bh0 = *(const bf16x8*)(wh0 + ko);
        bf16x8 bl0 = *(const bf16x8*)(wl0 + ko);
        bf16x8 bh1 = *(const bf16x8*)(wh1 + ko);
        bf16x8 bl1 = *(const bf16x8*)(wl1 + ko);
        acc0 = __builtin_amdgcn_mfma_f32_16x16x32_bf16(ahi, bh0, acc0, 0, 0, 0);
        acc0 = __builtin_amdgcn_mfma_f32_16x16x32_bf16(ahi, bl0, acc0, 0, 0, 0);
        acc0 = __builtin_amdgcn_mfma_f32_16x16x32_bf16(alo, bh0, acc0, 0, 0, 0);
        acc1 = __builtin_amdgcn_mfma_f32_16x16x32_bf16(ahi, bh1, acc1, 0, 0, 0);
        acc1 = __builtin_amdgcn_mfma_f32_16x16x32_bf16(ahi, bl1, acc1, 0, 0, 0);
        acc1 = __builtin_amdgcn_mfma_f32_16x16x32_bf16(alo, bh1, acc1, 0, 0, 0);
    }
    float bias0 = Wb[o0 + m], bias1 = Wb[o0 + 16 + m];
    #pragma unroll
    for (int reg = 0; reg < 4; ++reg) {
        int row = quad * 4 + reg;
        whs[row][o0 + m] = acc0[reg] + bias0;
        whs[row][o0 + 16 + m] = acc1[reg] + bias1;
    }
    __syncthreads();
    {   // WhT writer: 2 threads per o, 8 n each
        int o = t >> 1, half = t & 1;
        u16x8 v8;
        #pragma unroll
        for (int r = 0; r < 8; ++r) v8[r] = (short)f2b(whs[half * 8 + r][o]);
        *(u16x8*)(WhT + (size_t)(b * FOUT + o) * NN + n0 + half * 8) = v8;
    }
    {   // e-dots + exp tables
        int outi = t >> 1, half = t & 1;
        int i = outi >> 3, d = outi & 7, hh = d & 3, side = d >> 2;
        const float* arow = attw + hh * (2 * FOUT) + side * FOUT + half * 64;
        float s = 0.f;
        #pragma unroll 8
        for (int k = 0; k < 64; ++k) s = fmaf(whs[i][half * 64 + k], arow[k], s);
        s += __shfl_xor(s, 1);
        if (half == 0) {
            float p = __expf(s), n = __expf(NEG_SLOPE * s);
            if (side == 0) {
                ELpair[(size_t)(b * NH + hh) * NN + n0 + i] = make_float2(p, n);
            } else {
                ERf[((size_t)b * NN + n0 + i) * NH + hh] = make_float2(p, n);
            }
        }
    }
}

// ---------------------------------------------------------------------------
// K2 v2 (per-head unnormalized + epilogue divide):
// per block = (b, 16 i-rows) x ALL 2048 j, grid (128,4) = 512 blocks, 2/CU.
// Per 256-j chunk: build 4 per-head UNNORMALIZED bf16 weight tiles in LDS
// (uw_h = bit * max(elp_h*erp_h, eln_h*ern_h)), then each wave MFMAs its
// B-fragment against all 4 head tiles (B-reuse 4:1 — the R5 fix).
// Denominators S_h[i] accumulate in builder registers (sum of the SAME
// rounded bf16 weights), one shfl_xor reduce at the end; epilogue divides.
// Phase-1 j-sweep deleted entirely (~40% of pair-sweep VALU).
// ---------------------------------------------------------------------------
__global__ __launch_bounds__(512, 4) void k2_fused(
    const unsigned short* __restrict__ WhT, const float2* __restrict__ ERf,
    const float2* __restrict__ ELpair, const u64* __restrict__ mask,
    float* __restrict__ out) {
    __shared__ unsigned short wt[NH][16][264];   // 33.8 KB: per-head uw tiles
    __shared__ u64 mws[16][32];                  // 4 KB: full-row mask words
    __shared__ float el_s[16][8];                // 512 B: elp/eln per (i,h)
    __shared__ float S_s[16][NH];                // 256 B: denominators
    int t = threadIdx.x;
    int b = blockIdx.y, i0 = blockIdx.x * 16;
    int lane = t & 63, wv = t >> 6;
    int m = lane & 15, quad = lane >> 4;

    {   // stage mask words: 512 words, 1/thread
        int r = t >> 5, w = t & 31;
        mws[r][w] = mask[(size_t)(i0 + r) * 32 + w];
    }
    if (t < 128) {  // stage EL pairs: t = i*8 + h*2 + s
        int i = t >> 3, d = t & 7, hh = d >> 1, s = d & 1;
        float2 e2 = ELpair[(size_t)(b * NH + hh) * NN + i0 + i];
        el_s[i][hh * 2 + s] = s ? e2.y : e2.x;
    }
    __syncthreads();

    int ir0 = wv * 2, ir1 = ir0 + 1;             // the 2 rows this wave builds
    float4 c00 = *(float4*)&el_s[ir0][0];        // row0: h0p h0n h1p h1n
    float4 c01 = *(float4*)&el_s[ir0][4];        //       h2p h2n h3p h3n
    float4 c10 = *(float4*)&el_s[ir1][0];
    float4 c11 = *(float4*)&el_s[ir1][4];

    const unsigned short* bp = WhT + (size_t)(b * FOUT + wv * 16 + m) * NN;
    f32x4 acc[NH];
    #pragma unroll
    for (int hh = 0; hh < NH; ++hh) acc[hh] = (f32x4){0.f, 0.f, 0.f, 0.f};
    float sp0[NH] = {0.f, 0.f, 0.f, 0.f};        // per-lane S partials, row0
    float sp1[NH] = {0.f, 0.f, 0.f, 0.f};        // row1

    for (int ch = 0; ch < 8; ++ch) {
        int j0 = ch * 256;
        __syncthreads();                          // wt free to overwrite
        bf16x8 bfr[8];                            // B fragments (L2, reused x4)
        #pragma unroll
        for (int ks = 0; ks < 8; ++ks)
            bfr[ks] = *(const bf16x8*)(bp + j0 + ks * 32 + quad * 8);
        #pragma unroll
        for (int q = 0; q < 4; ++q) {
            int jg = j0 + q * 64 + lane;
            const float4* ef = (const float4*)(ERf + ((size_t)b * NN + jg) * NH);
            float4 e0 = ef[0], e1 = ef[1];        // h0p h0n h1p h1n / h2..h3
            bool bit0 = (mws[ir0][ch * 4 + q] >> lane) & 1ull;
            bool bit1 = (mws[ir1][ch * 4 + q] >> lane) & 1ull;
            {   // row 0
                float w0 = fmaxf(c00.x * e0.x, c00.y * e0.y);
                float w1 = fmaxf(c00.z * e0.z, c00.w * e0.w);
                float w2 = fmaxf(c01.x * e1.x, c01.y * e1.y);
                float w3 = fmaxf(c01.z * e1.z, c01.w * e1.w);
                unsigned short u0 = bit0 ? f2b_fast(w0) : 0;
                unsigned short u1 = bit0 ? f2b_fast(w1) : 0;
                unsigned short u2 = bit0 ? f2b_fast(w2) : 0;
                unsigned short u3 = bit0 ? f2b_fast(w3) : 0;
                wt[0][ir0][q * 64 + lane] = u0;
                wt[1][ir0][q * 64 + lane] = u1;
                wt[2][ir0][q * 64 + lane] = u2;
                wt[3][ir0][q * 64 + lane] = u3;
                sp0[0] += b2f(u0); sp0[1] += b2f(u1);
                sp0[2] += b2f(u2); sp0[3] += b2f(u3);
            }
            {   // row 1
                float w0 = fmaxf(c10.x * e0.x, c10.y * e0.y);
                float w1 = fmaxf(c10.z * e0.z, c10.w * e0.w);
                float w2 = fmaxf(c11.x * e1.x, c11.y * e1.y);
                float w3 = fmaxf(c11.z * e1.z, c11.w * e1.w);
                unsigned short u0 = bit1 ? f2b_fast(w0) : 0;
                unsigned short u1 = bit1 ? f2b_fast(w1) : 0;
                unsigned short u2 = bit1 ? f2b_fast(w2) : 0;
                unsigned short u3 = bit1 ? f2b_fast(w3) : 0;
                wt[0][ir1][q * 64 + lane] = u0;
                wt[1][ir1][q * 64 + lane] = u1;
                wt[2][ir1][q * 64 + lane] = u2;
                wt[3][ir1][q * 64 + lane] = u3;
                sp1[0] += b2f(u0); sp1[1] += b2f(u1);
                sp1[2] += b2f(u2); sp1[3] += b2f(u3);
            }
        }
        __syncthreads();
        #pragma unroll
        for (int ks = 0; ks < 8; ++ks) {          // 1 bfr feeds 4 MFMAs
            #pragma unroll
            for (int hh = 0; hh < NH; ++hh) {
                bf16x8 a = *(bf16x8*)&wt[hh][m][ks * 32 + quad * 8];
                acc[hh] = __builtin_amdgcn_mfma_f32_16x16x32_bf16(a, bfr[ks], acc[hh], 0, 0, 0);
            }
        }
    }
    // ---- S reduce across the 64 builder lanes (each covered j = ch*256+q*64+lane)
    #pragma unroll
    for (int hh = 0; hh < NH; ++hh) {
        #pragma unroll
        for (int s = 1; s < 64; s <<= 1) {
            sp0[hh] += __shfl_xor(sp0[hh], s);
            sp1[hh] += __shfl_xor(sp1[hh], s);
        }
    }
    if (lane == 0) {
        #pragma unroll
        for (int hh = 0; hh < NH; ++hh) {
            S_s[ir0][hh] = sp0[hh];
            S_s[ir1][hh] = sp1[hh];
        }
    }
    __syncthreads();
    // ---- epilogue: out = relu(0.25 * sum_h acc_h / S_h)
    #pragma unroll
    for (int reg = 0; reg < 4; ++reg) {
        int row = quad * 4 + reg;
        float v = 0.f;
        #pragma unroll
        for (int hh = 0; hh < NH; ++hh) {
            float S = S_s[row][hh];
            float iv = (S > 0.f) ? 1.f / S : 0.f;
            v += acc[hh][reg] * iv;
        }
        out[((size_t)b * NN + i0 + row) * FOUT + wv * 16 + m] =
            fmaxf(0.25f * v, 0.f);
    }
}

extern "C" void kernel_launch(void* const* d_in, const int* in_sizes, int n_in,
                              void* d_out, int out_size, void* d_ws, size_t ws_size,
                              hipStream_t stream) {
    const float* h    = (const float*)d_in[0];
    const int* adj    = (const int*)d_in[1];
    const float* Ww   = (const float*)d_in[2];
    const float* Wb   = (const float*)d_in[3];
    const float* attw = (const float*)d_in[4];
    float* out = (float*)d_out;
    char* ws = (char*)d_ws;
    // workspace layout (~3.3 MB)
    unsigned short* Whi = (unsigned short*)(ws);                 // 64 KB
    unsigned short* Wlo = (unsigned short*)(ws + 65536);         // 64 KB
    unsigned short* WhT = (unsigned short*)(ws + 131072);        // 2 MB [b][o][n] bf16
    float2*       ELpair = (float2*)(ws + 2228224);              // 256 KB [bh][i]
    float2*       ERf    = (float2*)(ws + 2490368);              // 256 KB [b][j][h] f32 pair
    u64*          mask   = (u64*)(ws + 2752512);                 // 512 KB

    k0_prep<<<dim3(128 + NN), dim3(256), 0, stream>>>(Ww, Whi, Wlo, adj, mask);
    k1_wh<<<dim3(BB * NN / 16), dim3(256), 0, stream>>>(h, Whi, Wlo, Wb, attw,
                                                        WhT, ELpair, ERf);
    k2_fused<<<dim3(NN / 16, BB), dim3(512), 0, stream>>>(WhT, ERf, ELpair,
                                                          mask, out);
}

// Round 16
// 128.508 us; speedup vs baseline: 1.1662x; 1.1269x over previous
//
#include <hip/hip_runtime.h>
#include <stdint.h>

#define BB 4
#define NN 2048
#define FIN 256
#define FOUT 128
#define NH 4
#define NEG_SLOPE 0.2f

typedef short bf16x8 __attribute__((ext_vector_type(8)));
typedef unsigned short u16x8 __attribute__((ext_vector_type(8)));
typedef float f32x4 __attribute__((ext_vector_type(4)));
typedef unsigned long long u64;

__device__ inline float b2f(unsigned short u) {
    union { unsigned int i; float f; } x; x.i = ((unsigned int)u) << 16; return x.f;
}
__device__ inline unsigned short f2b(float f) {   // fp32 -> bf16 RNE
    union { float f; unsigned int i; } x; x.f = f;
    unsigned int r = x.i + 0x7fffu + ((x.i >> 16) & 1u);
    return (unsigned short)(r >> 16);
}
__device__ inline unsigned short f2b_fast(float f) {  // round-half-up (f >= 0 here)
    union { float f; unsigned int i; } x; x.f = f;
    return (unsigned short)((x.i + 0x8000u) >> 16);
}

// ---------------------------------------------------------------------------
// NOTE (timing model, R5): the harness's workspace poison-fill (~43 µs)
// runs INSIDE the timed window each iteration. Controllable budget = dur - 43.
// NOTE (R2): no cross-block fences — device-scope __threadfence cost ~120 µs.
// NOTE (R10): LDS-staged A-tiles cost 1KB LDS read per MFMA (~31 µs/CU here);
// A must be built in fragment registers directly.
// ---------------------------------------------------------------------------

// ---------------------------------------------------------------------------
// k0_prep (fused): blocks [0,128): W fp32 -> bf16 hi/lo split.
// blocks [128,128+NN): adj row -> 32 u64 bitmask words.
// ---------------------------------------------------------------------------
__global__ __launch_bounds__(256) void k0_prep(const float* __restrict__ Ww,
                                               unsigned short* __restrict__ Whi,
                                               unsigned short* __restrict__ Wlo,
                                               const int* __restrict__ adj,
                                               u64* __restrict__ mask) {
    int bid = blockIdx.x;
    if (bid < 128) {
        int idx = bid * 256 + threadIdx.x;   // 32768 elems
        float v = Ww[idx];
        unsigned short hb = f2b(v);
        Whi[idx] = hb;
        Wlo[idx] = f2b(v - b2f(hb));
    } else {
        int row = bid - 128;
        int wave = threadIdx.x >> 6, lane = threadIdx.x & 63;
        #pragma unroll
        for (int it = 0; it < 8; ++it) {
            int w = it * 4 + wave;
            int j = w * 64 + lane;
            u64 m = __ballot(adj[(size_t)row * NN + j] != 0);
            if (lane == 0) mask[row * 32 + w] = m;
        }
    }
}

// ---------------------------------------------------------------------------
// K1 (MFMA): Wh[16 rows][128 o] = h_tile @ W^T + b, split-bf16 (hh+hl+lh).
// Epilogue: WhT bf16 [b][o][n]; exp tables (fp32):
//   ELpair[b*4+h][i]   = (exp(eL), exp(0.2 eL)) fp32x2
//   ERf  [b][j][h]     = (exp(eR), exp(0.2 eR)) fp32x2
// ---------------------------------------------------------------------------
__global__ __launch_bounds__(256) void k1_wh(
    const float* __restrict__ h, const unsigned short* __restrict__ Whi,
    const unsigned short* __restrict__ Wlo, const float* __restrict__ Wb,
    const float* __restrict__ attw, unsigned short* __restrict__ WhT,
    float2* __restrict__ ELpair, float2* __restrict__ ERf) {
    __shared__ unsigned short Ahi[16][264];
    __shared__ unsigned short Alo[16][264];
    __shared__ float whs[16][132];
    int t = threadIdx.x;
    int b = blockIdx.x >> 7;
    int n0 = (blockIdx.x & 127) * 16;
    {
        int r = t >> 4, c = (t & 15) * 16;
        const float* hp = h + ((size_t)(b * NN + n0 + r)) * FIN + c;
        u16x8 hi0, hi1, lo0, lo1;
        #pragma unroll
        for (int q = 0; q < 4; ++q) {
            float4 v = *(const float4*)(hp + q * 4);
            float vv[4] = {v.x, v.y, v.z, v.w};
            #pragma unroll
            for (int e = 0; e < 4; ++e) {
                int idx = q * 4 + e;
                unsigned short hb = f2b(vv[e]);
                unsigned short lb = f2b(vv[e] - b2f(hb));
                if (idx < 8) { hi0[idx] = (short)hb; lo0[idx] = (short)lb; }
                else         { hi1[idx - 8] = (short)hb; lo1[idx - 8] = (short)lb; }
            }
        }
        *(u16x8*)&Ahi[r][c] = *(u16x8*)&hi0;
        *(u16x8*)&Ahi[r][c + 8] = *(u16x8*)&hi1;
        *(u16x8*)&Alo[r][c] = *(u16x8*)&lo0;
        *(u16x8*)&Alo[r][c + 8] = *(u16x8*)&lo1;
    }
    __syncthreads();
    int lane = t & 63, wv = t >> 6;
    int m = lane & 15, quad = lane >> 4;
    int o0 = wv * 32;
    f32x4 acc0 = {0.f, 0.f, 0.f, 0.f}, acc1 = {0.f, 0.f, 0.f, 0.f};
    const unsigned short* wh0 = Whi + (size_t)(o0 + m) * FIN;
    const unsigned short* wl0 = Wlo + (size_t)(o0 + m) * FIN;
    const unsigned short* wh1 = Whi + (size_t)(o0 + 16 + m) * FIN;
    const unsigned short* wl1 = Wlo + (size_t)(o0 + 16 + m) * FIN;
    #pragma unroll
    for (int ks = 0; ks < 8; ++ks) {
        int ko = ks * 32 + quad * 8;
        bf16x8 ahi = *(bf16x8*)&Ahi[m][ko];
        bf16x8 alo = *(bf16x8*)&Alo[m][ko];
        bf16x8 bh0 = *(const bf16x8*)(wh0 + ko);
        bf16x8 bl0 = *(const bf16x8*)(wl0 + ko);
        bf16x8 bh1 = *(const bf16x8*)(wh1 + ko);
        bf16x8 bl1 = *(const bf16x8*)(wl1 + ko);
        acc0 = __builtin_amdgcn_mfma_f32_16x16x32_bf16(ahi, bh0, acc0, 0, 0, 0);
        acc0 = __builtin_amdgcn_mfma_f32_16x16x32_bf16(ahi, bl0, acc0, 0, 0, 0);
        acc0 = __builtin_amdgcn_mfma_f32_16x16x32_bf16(alo, bh0, acc0, 0, 0, 0);
        acc1 = __builtin_amdgcn_mfma_f32_16x16x32_bf16(ahi, bh1, acc1, 0, 0, 0);
        acc1 = __builtin_amdgcn_mfma_f32_16x16x32_bf16(ahi, bl1, acc1, 0, 0, 0);
        acc1 = __builtin_amdgcn_mfma_f32_16x16x32_bf16(alo, bh1, acc1, 0, 0, 0);
    }
    float bias0 = Wb[o0 + m], bias1 = Wb[o0 + 16 + m];
    #pragma unroll
    for (int reg = 0; reg < 4; ++reg) {
        int row = quad * 4 + reg;
        whs[row][o0 + m] = acc0[reg] + bias0;
        whs[row][o0 + 16 + m] = acc1[reg] + bias1;
    }
    __syncthreads();
    {   // WhT writer: 2 threads per o, 8 n each
        int o = t >> 1, half = t & 1;
        u16x8 v8;
        #pragma unroll
        for (int r = 0; r < 8; ++r) v8[r] = (short)f2b(whs[half * 8 + r][o]);
        *(u16x8*)(WhT + (size_t)(b * FOUT + o) * NN + n0 + half * 8) = v8;
    }
    {   // e-dots + exp tables
        int outi = t >> 1, half = t & 1;
        int i = outi >> 3, d = outi & 7, hh = d & 3, side = d >> 2;
        const float* arow = attw + hh * (2 * FOUT) + side * FOUT + half * 64;
        float s = 0.f;
        #pragma unroll 8
        for (int k = 0; k < 64; ++k) s = fmaf(whs[i][half * 64 + k], arow[k], s);
        s += __shfl_xor(s, 1);
        if (half == 0) {
            float p = __expf(s), n = __expf(NEG_SLOPE * s);
            if (side == 0) {
                ELpair[(size_t)(b * NH + hh) * NN + n0 + i] = make_float2(p, n);
            } else {
                ERf[((size_t)b * NN + n0 + i) * NH + hh] = make_float2(p, n);
            }
        }
    }
}

// ---------------------------------------------------------------------------
// K2 v3 (register-fragment A build — no LDS A-tile, no main-loop barriers):
// grid (NN/32, BB) = 256 blocks x 512 thr (8 waves), 1 block/CU.
// Wave = (isub 2) x (oq 2) x (kp 2): 16 i-rows, 64 o, ks = kp,kp+2,...
// Per ks: lane (m,quad) builds its OWN A-fragment elems (8 j x 4 heads)
// from LDS-broadcast ERf + mask bits + per-row EL regs -> 4 per-head frags;
// MFMA vs 4 B-frags (4:1 head reuse; B from L2) + 1 ones-MFMA per head
// accumulating the softmax denominator in D-row layout for free.
// Tail: cross-kp C/S reduce through reused LDS, divide, relu, store.
// ---------------------------------------------------------------------------
__global__ __launch_bounds__(512, 2) void k2_reg(
    const unsigned short* __restrict__ WhT, const float2* __restrict__ ERf,
    const float2* __restrict__ ELpair, const u64* __restrict__ mask,
    float* __restrict__ out) {
    __shared__ char smem[65536 + 8448 + 1024];   // 73.2 KB
    float4* erf4 = (float4*)smem;                // [2048 j][2] float4 (64 KB)
    u64* mlds = (u64*)(smem + 65536);            // [32][33] padded (8448 B)
    float* sred = (float*)(smem + 65536 + 8448); // [4p][4h][4r][4quad] (1 KB)
    int t = threadIdx.x;
    int b = blockIdx.y, i0 = blockIdx.x * 32;
    int lane = t & 63, wv = t >> 6;
    int m = lane & 15, quad = lane >> 4;
    int isub = wv & 1, oq = (wv >> 1) & 1, kp = wv >> 2;

    {   // stage ERf for this b: 64 KB, coalesced float4
        const float4* src = (const float4*)(ERf + (size_t)b * NN * NH);
        #pragma unroll
        for (int i = 0; i < 8; ++i) erf4[t + i * 512] = src[t + i * 512];
    }
    {   // stage masks: 32 rows x 32 words, padded stride 33 (bank-spread)
        #pragma unroll
        for (int i = 0; i < 2; ++i) {
            int idx = t + i * 512;
            int r = idx >> 5, w = idx & 31;
            mlds[r * 33 + w] = mask[(size_t)(i0 + r) * 32 + w];
        }
    }
    int irow = i0 + isub * 16 + m;               // this lane's A row
    float elp[NH], eln[NH];
    #pragma unroll
    for (int hh = 0; hh < NH; ++hh) {
        float2 e2 = ELpair[(size_t)(b * NH + hh) * NN + irow];
        elp[hh] = e2.x; eln[hh] = e2.y;
    }
    __syncthreads();

    bf16x8 ones;
    #pragma unroll
    for (int e = 0; e < 8; ++e) ones[e] = (short)0x3F80;   // bf16 1.0

    const unsigned short* bp0 = WhT + (size_t)(b * FOUT + oq * 64 +  0 + m) * NN;
    const unsigned short* bp1 = WhT + (size_t)(b * FOUT + oq * 64 + 16 + m) * NN;
    const unsigned short* bp2 = WhT + (size_t)(b * FOUT + oq * 64 + 32 + m) * NN;
    const unsigned short* bp3 = WhT + (size_t)(b * FOUT + oq * 64 + 48 + m) * NN;

    f32x4 acc[4][4];                             // [o-frag f][head h]
    f32x4 sacc[4];                               // [head h] denominator
    #pragma unroll
    for (int f = 0; f < 4; ++f)
        #pragma unroll
        for (int hh = 0; hh < NH; ++hh) acc[f][hh] = (f32x4){0.f, 0.f, 0.f, 0.f};
    #pragma unroll
    for (int hh = 0; hh < NH; ++hh) sacc[hh] = (f32x4){0.f, 0.f, 0.f, 0.f};

    int mr = isub * 16 + m;                      // local mask row

    for (int it = 0; it < 32; ++it) {
        int ks = (it << 1) | kp;
        int jb = ks * 32 + quad * 8;             // lane's 8-j window
        bf16x8 bfr0 = *(const bf16x8*)(bp0 + jb);
        bf16x8 bfr1 = *(const bf16x8*)(bp1 + jb);
        bf16x8 bfr2 = *(const bf16x8*)(bp2 + jb);
        bf16x8 bfr3 = *(const bf16x8*)(bp3 + jb);
        u64 w64 = mlds[mr * 33 + (ks >> 1)];
        unsigned mb = (unsigned)(w64 >> (((ks & 1) << 5) + (quad << 3))) & 0xFFu;
        bf16x8 af0, af1, af2, af3;
        #pragma unroll
        for (int e = 0; e < 8; ++e) {
            float4 e0 = erf4[(jb + e) * 2];      // h0p h0n h1p h1n
            float4 e1 = erf4[(jb + e) * 2 + 1];  // h2p h2n h3p h3n
            bool bit = (mb >> e) & 1u;
            float w0 = fmaxf(elp[0] * e0.x, eln[0] * e0.y);
            float w1 = fmaxf(elp[1] * e0.z, eln[1] * e0.w);
            float w2 = fmaxf(elp[2] * e1.x, eln[2] * e1.y);
            float w3 = fmaxf(elp[3] * e1.z, eln[3] * e1.w);
            af0[e] = bit ? (short)f2b_fast(w0) : (short)0;
            af1[e] = bit ? (short)f2b_fast(w1) : (short)0;
            af2[e] = bit ? (short)f2b_fast(w2) : (short)0;
            af3[e] = bit ? (short)f2b_fast(w3) : (short)0;
        }
        sacc[0] = __builtin_amdgcn_mfma_f32_16x16x32_bf16(af0, ones, sacc[0], 0, 0, 0);
        sacc[1] = __builtin_amdgcn_mfma_f32_16x16x32_bf16(af1, ones, sacc[1], 0, 0, 0);
        sacc[2] = __builtin_amdgcn_mfma_f32_16x16x32_bf16(af2, ones, sacc[2], 0, 0, 0);
        sacc[3] = __builtin_amdgcn_mfma_f32_16x16x32_bf16(af3, ones, sacc[3], 0, 0, 0);
        acc[0][0] = __builtin_amdgcn_mfma_f32_16x16x32_bf16(af0, bfr0, acc[0][0], 0, 0, 0);
        acc[0][1] = __builtin_amdgcn_mfma_f32_16x16x32_bf16(af1, bfr0, acc[0][1], 0, 0, 0);
        acc[0][2] = __builtin_amdgcn_mfma_f32_16x16x32_bf16(af2, bfr0, acc[0][2], 0, 0, 0);
        acc[0][3] = __builtin_amdgcn_mfma_f32_16x16x32_bf16(af3, bfr0, acc[0][3], 0, 0, 0);
        acc[1][0] = __builtin_amdgcn_mfma_f32_16x16x32_bf16(af0, bfr1, acc[1][0], 0, 0, 0);
        acc[1][1] = __builtin_amdgcn_mfma_f32_16x16x32_bf16(af1, bfr1, acc[1][1], 0, 0, 0);
        acc[1][2] = __builtin_amdgcn_mfma_f32_16x16x32_bf16(af2, bfr1, acc[1][2], 0, 0, 0);
        acc[1][3] = __builtin_amdgcn_mfma_f32_16x16x32_bf16(af3, bfr1, acc[1][3], 0, 0, 0);
        acc[2][0] = __builtin_amdgcn_mfma_f32_16x16x32_bf16(af0, bfr2, acc[2][0], 0, 0, 0);
        acc[2][1] = __builtin_amdgcn_mfma_f32_16x16x32_bf16(af1, bfr2, acc[2][1], 0, 0, 0);
        acc[2][2] = __builtin_amdgcn_mfma_f32_16x16x32_bf16(af2, bfr2, acc[2][2], 0, 0, 0);
        acc[2][3] = __builtin_amdgcn_mfma_f32_16x16x32_bf16(af3, bfr2, acc[2][3], 0, 0, 0);
        acc[3][0] = __builtin_amdgcn_mfma_f32_16x16x32_bf16(af0, bfr3, acc[3][0], 0, 0, 0);
        acc[3][1] = __builtin_amdgcn_mfma_f32_16x16x32_bf16(af1, bfr3, acc[3][1], 0, 0, 0);
        acc[3][2] = __builtin_amdgcn_mfma_f32_16x16x32_bf16(af2, bfr3, acc[3][2], 0, 0, 0);
        acc[3][3] = __builtin_amdgcn_mfma_f32_16x16x32_bf16(af3, bfr3, acc[3][3], 0, 0, 0);
    }
    __syncthreads();                             // ERf reads done; reuse smem

    float* cred = (float*)smem;                  // [4p][4f][4h][4r][64] = 64 KB
    int p = wv & 3;                              // pair id (isub + 2*oq)
    if (kp == 1) {
        #pragma unroll
        for (int f = 0; f < 4; ++f)
            #pragma unroll
            for (int hh = 0; hh < NH; ++hh)
                #pragma unroll
                for (int r = 0; r < 4; ++r)
                    cred[(((p * 4 + f) * 4 + hh) * 4 + r) * 64 + lane] = acc[f][hh][r];
        if (m == 0) {
            #pragma unroll
            for (int hh = 0; hh < NH; ++hh)
                #pragma unroll
                for (int r = 0; r < 4; ++r)
                    sred[((p * 4 + hh) * 4 + r) * 4 + quad] = sacc[hh][r];
        }
    }
    __syncthreads();
    if (kp == 0) {
        #pragma unroll
        for (int r = 0; r < 4; ++r) {
            float inv[NH];
            #pragma unroll
            for (int hh = 0; hh < NH; ++hh) {
                float S = sacc[hh][r] + sred[((p * 4 + hh) * 4 + r) * 4 + quad];
                inv[hh] = (S > 0.f) ? 1.f / S : 0.f;
            }
            int orow = i0 + isub * 16 + quad * 4 + r;
            #pragma unroll
            for (int f = 0; f < 4; ++f) {
                float v = 0.f;
                #pragma unroll
                for (int hh = 0; hh < NH; ++hh)
                    v += (acc[f][hh][r] +
                          cred[(((p * 4 + f) * 4 + hh) * 4 + r) * 64 + lane]) * inv[hh];
                out[((size_t)b * NN + orow) * FOUT + oq * 64 + f * 16 + m] =
                    fmaxf(0.25f * v, 0.f);
            }
        }
    }
}

extern "C" void kernel_launch(void* const* d_in, const int* in_sizes, int n_in,
                              void* d_out, int out_size, void* d_ws, size_t ws_size,
                              hipStream_t stream) {
    const float* h    = (const float*)d_in[0];
    const int* adj    = (const int*)d_in[1];
    const float* Ww   = (const float*)d_in[2];
    const float* Wb   = (const float*)d_in[3];
    const float* attw = (const float*)d_in[4];
    float* out = (float*)d_out;
    char* ws = (char*)d_ws;
    // workspace layout (~3.3 MB)
    unsigned short* Whi = (unsigned short*)(ws);                 // 64 KB
    unsigned short* Wlo = (unsigned short*)(ws + 65536);         // 64 KB
    unsigned short* WhT = (unsigned short*)(ws + 131072);        // 2 MB [b][o][n] bf16
    float2*       ELpair = (float2*)(ws + 2228224);              // 256 KB [bh][i]
    float2*       ERf    = (float2*)(ws + 2490368);              // 256 KB [b][j][h] f32 pair
    u64*          mask   = (u64*)(ws + 2752512);                 // 512 KB

    k0_prep<<<dim3(128 + NN), dim3(256), 0, stream>>>(Ww, Whi, Wlo, adj, mask);
    k1_wh<<<dim3(BB * NN / 16), dim3(256), 0, stream>>>(h, Whi, Wlo, Wb, attw,
                                                        WhT, ELpair, ERf);
    k2_reg<<<dim3(NN / 32, BB), dim3(512), 0, stream>>>(WhT, ERf, ELpair,
                                                        mask, out);
}

// Round 18
// 125.390 us; speedup vs baseline: 1.1952x; 1.0249x over previous
//
#include <hip/hip_runtime.h>
#include <stdint.h>

#define BB 4
#define NN 2048
#define FIN 256
#define FOUT 128
#define NH 4
#define NEG_SLOPE 0.2f

typedef short bf16x8 __attribute__((ext_vector_type(8)));
typedef unsigned short u16x8 __attribute__((ext_vector_type(8)));
typedef float f32x4 __attribute__((ext_vector_type(4)));
typedef unsigned long long u64;

__device__ inline float b2f(unsigned short u) {
    union { unsigned int i; float f; } x; x.i = ((unsigned int)u) << 16; return x.f;
}
__device__ inline unsigned short f2b(float f) {   // fp32 -> bf16 RNE
    union { float f; unsigned int i; } x; x.f = f;
    unsigned int r = x.i + 0x7fffu + ((x.i >> 16) & 1u);
    return (unsigned short)(r >> 16);
}
__device__ inline unsigned short f2b_fast(float f) {  // round-half-up (f >= 0 here)
    union { float f; unsigned int i; } x; x.f = f;
    return (unsigned short)((x.i + 0x8000u) >> 16);
}

// ---------------------------------------------------------------------------
// NOTE (timing model, R5): the harness's workspace poison-fill (~43 µs)
// runs INSIDE the timed window each iteration. Controllable budget = dur - 43.
// NOTE (R2): no cross-block fences — device-scope __threadfence cost ~120 µs.
// NOTE (R10): LDS-staged A-tiles cost 1KB LDS read per MFMA; A must be built
// in fragment registers. NOTE (R16): ERf broadcast reads were a 4-way bank
// conflict (quads 256B apart). NOTE (R17): additive skew g+((g>>4)&3) is NOT
// injective (3/64 slots collide -> absmax 0.097). Skews must be bijective:
// XOR skew g ^ (((g>>4)&3)<<1) stays within each 16-float4 block.
// ---------------------------------------------------------------------------

// ---------------------------------------------------------------------------
// k0_prep: W fp32 -> bf16 hi/lo split only (mask pack lives in k1).
// ---------------------------------------------------------------------------
__global__ __launch_bounds__(256) void k0_prep(const float* __restrict__ Ww,
                                               unsigned short* __restrict__ Whi,
                                               unsigned short* __restrict__ Wlo) {
    int idx = blockIdx.x * 256 + threadIdx.x;   // 32768 elems
    float v = Ww[idx];
    unsigned short hb = f2b(v);
    Whi[idx] = hb;
    Wlo[idx] = f2b(v - b2f(hb));
}

// ---------------------------------------------------------------------------
// K1 (MFMA): blocks [0,512): Wh tile + WhT/EL/ER tables.
// blocks [512, 512+NN): adj row -> 32 u64 bitmask words (overlaps Wh compute).
// ---------------------------------------------------------------------------
__global__ __launch_bounds__(256) void k1_wh(
    const float* __restrict__ h, const unsigned short* __restrict__ Whi,
    const unsigned short* __restrict__ Wlo, const float* __restrict__ Wb,
    const float* __restrict__ attw, unsigned short* __restrict__ WhT,
    float2* __restrict__ ELpair, float2* __restrict__ ERf,
    const int* __restrict__ adj, u64* __restrict__ mask) {
    if (blockIdx.x >= BB * NN / 16) {            // ---- mask-pack blocks
        int row = blockIdx.x - BB * NN / 16;
        int wave = threadIdx.x >> 6, lane = threadIdx.x & 63;
        #pragma unroll
        for (int it = 0; it < 8; ++it) {
            int w = it * 4 + wave;
            int j = w * 64 + lane;
            u64 mm = __ballot(adj[(size_t)row * NN + j] != 0);
            if (lane == 0) mask[row * 32 + w] = mm;
        }
        return;
    }
    __shared__ unsigned short Ahi[16][264];
    __shared__ unsigned short Alo[16][264];
    __shared__ float whs[16][132];
    int t = threadIdx.x;
    int b = blockIdx.x >> 7;
    int n0 = (blockIdx.x & 127) * 16;
    {
        int r = t >> 4, c = (t & 15) * 16;
        const float* hp = h + ((size_t)(b * NN + n0 + r)) * FIN + c;
        u16x8 hi0, hi1, lo0, lo1;
        #pragma unroll
        for (int q = 0; q < 4; ++q) {
            float4 v = *(const float4*)(hp + q * 4);
            float vv[4] = {v.x, v.y, v.z, v.w};
            #pragma unroll
            for (int e = 0; e < 4; ++e) {
                int idx = q * 4 + e;
                unsigned short hb = f2b(vv[e]);
                unsigned short lb = f2b(vv[e] - b2f(hb));
                if (idx < 8) { hi0[idx] = (short)hb; lo0[idx] = (short)lb; }
                else         { hi1[idx - 8] = (short)hb; lo1[idx - 8] = (short)lb; }
            }
        }
        *(u16x8*)&Ahi[r][c] = *(u16x8*)&hi0;
        *(u16x8*)&Ahi[r][c + 8] = *(u16x8*)&hi1;
        *(u16x8*)&Alo[r][c] = *(u16x8*)&lo0;
        *(u16x8*)&Alo[r][c + 8] = *(u16x8*)&lo1;
    }
    __syncthreads();
    int lane = t & 63, wv = t >> 6;
    int m = lane & 15, quad = lane >> 4;
    int o0 = wv * 32;
    f32x4 acc0 = {0.f, 0.f, 0.f, 0.f}, acc1 = {0.f, 0.f, 0.f, 0.f};
    const unsigned short* wh0 = Whi + (size_t)(o0 + m) * FIN;
    const unsigned short* wl0 = Wlo + (size_t)(o0 + m) * FIN;
    const unsigned short* wh1 = Whi + (size_t)(o0 + 16 + m) * FIN;
    const unsigned short* wl1 = Wlo + (size_t)(o0 + 16 + m) * FIN;
    #pragma unroll
    for (int ks = 0; ks < 8; ++ks) {
        int ko = ks * 32 + quad * 8;
        bf16x8 ahi = *(bf16x8*)&Ahi[m][ko];
        bf16x8 alo = *(bf16x8*)&Alo[m][ko];
        bf16x8 bh0 = *(const bf16x8*)(wh0 + ko);
        bf16x8 bl0 = *(const bf16x8*)(wl0 + ko);
        bf16x8 bh1 = *(const bf16x8*)(wh1 + ko);
        bf16x8 bl1 = *(const bf16x8*)(wl1 + ko);
        acc0 = __builtin_amdgcn_mfma_f32_16x16x32_bf16(ahi, bh0, acc0, 0, 0, 0);
        acc0 = __builtin_amdgcn_mfma_f32_16x16x32_bf16(ahi, bl0, acc0, 0, 0, 0);
        acc0 = __builtin_amdgcn_mfma_f32_16x16x32_bf16(alo, bh0, acc0, 0, 0, 0);
        acc1 = __builtin_amdgcn_mfma_f32_16x16x32_bf16(ahi, bh1, acc1, 0, 0, 0);
        acc1 = __builtin_amdgcn_mfma_f32_16x16x32_bf16(ahi, bl1, acc1, 0, 0, 0);
        acc1 = __builtin_amdgcn_mfma_f32_16x16x32_bf16(alo, bh1, acc1, 0, 0, 0);
    }
    float bias0 = Wb[o0 + m], bias1 = Wb[o0 + 16 + m];
    #pragma unroll
    for (int reg = 0; reg < 4; ++reg) {
        int row = quad * 4 + reg;
        whs[row][o0 + m] = acc0[reg] + bias0;
        whs[row][o0 + 16 + m] = acc1[reg] + bias1;
    }
    __syncthreads();
    {   // WhT writer: 2 threads per o, 8 n each
        int o = t >> 1, half = t & 1;
        u16x8 v8;
        #pragma unroll
        for (int r = 0; r < 8; ++r) v8[r] = (short)f2b(whs[half * 8 + r][o]);
        *(u16x8*)(WhT + (size_t)(b * FOUT + o) * NN + n0 + half * 8) = v8;
    }
    {   // e-dots + exp tables
        int outi = t >> 1, half = t & 1;
        int i = outi >> 3, d = outi & 7, hh = d & 3, side = d >> 2;
        const float* arow = attw + hh * (2 * FOUT) + side * FOUT + half * 64;
        float s = 0.f;
        #pragma unroll 8
        for (int k = 0; k < 64; ++k) s = fmaf(whs[i][half * 64 + k], arow[k], s);
        s += __shfl_xor(s, 1);
        if (half == 0) {
            float p = __expf(s), n = __expf(NEG_SLOPE * s);
            if (side == 0) {
                ELpair[(size_t)(b * NH + hh) * NN + n0 + i] = make_float2(p, n);
            } else {
                ERf[((size_t)b * NN + n0 + i) * NH + hh] = make_float2(p, n);
            }
        }
    }
}

// ---------------------------------------------------------------------------
// K2 v5: register-fragment A build; waves = (isub 2) x (kp 4); each wave
// owns 16 i-rows x ALL 128 o (8 B-frags) x ks = kp, kp+4, ... (16 iters).
// Zero A-build duplication; ERf LDS uses BIJECTIVE XOR skew (R17 fix):
// store g ^ (((g>>4)&3)<<1), read (gb+e*2) ^ (quad<<1) -> quads land on
// disjoint bank groups {0-3}{8-11}{16-19}{24-27}; no collisions possible
// (XOR stays within each 16-float4 block). No main-loop barriers.
// Denominators via ones-MFMA (D-row layout). Tail: 4-way kp reduce through
// reused LDS, per-head rounds. grid (NN/32, BB) = 256 blocks x 512 thr.
// ---------------------------------------------------------------------------
__global__ __launch_bounds__(512, 2) void k2_reg(
    const unsigned short* __restrict__ WhT, const float2* __restrict__ ERf,
    const float2* __restrict__ ELpair, const u64* __restrict__ mask,
    float* __restrict__ out) {
    __shared__ char smem[65600 + 8448 + 1536];   // 73.8 KB
    float4* erf4 = (float4*)smem;                // XOR-skewed [4096] float4
    u64* mlds = (u64*)(smem + 65600);            // [32][33] padded
    float* sred = (float*)(smem + 65600 + 8448); // [3kp'][2isub][4h][4r][4quad]
    int t = threadIdx.x;
    int b = blockIdx.y, i0 = blockIdx.x * 32;
    int lane = t & 63, wv = t >> 6;
    int m = lane & 15, quad = lane >> 4;
    int isub = wv & 1, kp = wv >> 1;             // kp in 0..3

    {   // stage ERf for this b (bijective XOR-skewed destination)
        const float4* src = (const float4*)(ERf + (size_t)b * NN * NH);
        #pragma unroll
        for (int i = 0; i < 8; ++i) {
            int g = t + i * 512;
            erf4[g ^ (((g >> 4) & 3) << 1)] = src[g];
        }
    }
    {   // stage masks: 32 rows x 32 words, padded stride 33
        #pragma unroll
        for (int i = 0; i < 2; ++i) {
            int idx = t + i * 512;
            int r = idx >> 5, w = idx & 31;
            mlds[r * 33 + w] = mask[(size_t)(i0 + r) * 32 + w];
        }
    }
    int irow = i0 + isub * 16 + m;               // this lane's A row
    float elp[NH], eln[NH];
    #pragma unroll
    for (int hh = 0; hh < NH; ++hh) {
        float2 e2 = ELpair[(size_t)(b * NH + hh) * NN + irow];
        elp[hh] = e2.x; eln[hh] = e2.y;
    }
    __syncthreads();

    bf16x8 ones;
    #pragma unroll
    for (int e = 0; e < 8; ++e) ones[e] = (short)0x3F80;   // bf16 1.0

    const unsigned short* bp[8];
    #pragma unroll
    for (int f = 0; f < 8; ++f)
        bp[f] = WhT + (size_t)(b * FOUT + f * 16 + m) * NN + kp * 32 + quad * 8;

    f32x4 acc[8][NH];                            // [o-frag f][head h]
    f32x4 sacc[NH];                              // [head h] denominator
    #pragma unroll
    for (int f = 0; f < 8; ++f)
        #pragma unroll
        for (int hh = 0; hh < NH; ++hh) acc[f][hh] = (f32x4){0.f, 0.f, 0.f, 0.f};
    #pragma unroll
    for (int hh = 0; hh < NH; ++hh) sacc[hh] = (f32x4){0.f, 0.f, 0.f, 0.f};

    int mr = isub * 16 + m;                      // local mask row
    int qs = quad << 1;                          // XOR skew for reads

    for (int it = 0; it < 16; ++it) {
        int ks = (it << 2) | kp;
        int jb = ks * 32 + quad * 8;             // lane's 8-j window
        bf16x8 bfr[8];
        #pragma unroll
        for (int f = 0; f < 8; ++f) bfr[f] = *(const bf16x8*)(bp[f]);
        u64 w64 = mlds[mr * 33 + (ks >> 1)];
        unsigned mb = (unsigned)(w64 >> (((ks & 1) << 5) + (quad << 3))) & 0xFFu;
        int gb = jb * 2;                         // unskewed float4 base (mod16==0)
        bf16x8 af0, af1, af2, af3;
        #pragma unroll
        for (int e = 0; e < 8; ++e) {
            int a0 = (gb + e * 2) ^ qs;          // (g>>4)&3 == quad here
            float4 e0 = erf4[a0];                // h0p h0n h1p h1n
            float4 e1 = erf4[a0 + 1];            // h2p h2n h3p h3n
            bool bit = (mb >> e) & 1u;
            float w0 = fmaxf(elp[0] * e0.x, eln[0] * e0.y);
            float w1 = fmaxf(elp[1] * e0.z, eln[1] * e0.w);
            float w2 = fmaxf(elp[2] * e1.x, eln[2] * e1.y);
            float w3 = fmaxf(elp[3] * e1.z, eln[3] * e1.w);
            af0[e] = bit ? (short)f2b_fast(w0) : (short)0;
            af1[e] = bit ? (short)f2b_fast(w1) : (short)0;
            af2[e] = bit ? (short)f2b_fast(w2) : (short)0;
            af3[e] = bit ? (short)f2b_fast(w3) : (short)0;
        }
        sacc[0] = __builtin_amdgcn_mfma_f32_16x16x32_bf16(af0, ones, sacc[0], 0, 0, 0);
        sacc[1] = __builtin_amdgcn_mfma_f32_16x16x32_bf16(af1, ones, sacc[1], 0, 0, 0);
        sacc[2] = __builtin_amdgcn_mfma_f32_16x16x32_bf16(af2, ones, sacc[2], 0, 0, 0);
        sacc[3] = __builtin_amdgcn_mfma_f32_16x16x32_bf16(af3, ones, sacc[3], 0, 0, 0);
        #pragma unroll
        for (int f = 0; f < 8; ++f) {
            acc[f][0] = __builtin_amdgcn_mfma_f32_16x16x32_bf16(af0, bfr[f], acc[f][0], 0, 0, 0);
            acc[f][1] = __builtin_amdgcn_mfma_f32_16x16x32_bf16(af1, bfr[f], acc[f][1], 0, 0, 0);
            acc[f][2] = __builtin_amdgcn_mfma_f32_16x16x32_bf16(af2, bfr[f], acc[f][2], 0, 0, 0);
            acc[f][3] = __builtin_amdgcn_mfma_f32_16x16x32_bf16(af3, bfr[f], acc[f][3], 0, 0, 0);
        }
        #pragma unroll
        for (int f = 0; f < 8; ++f) bp[f] += 128;
    }
    __syncthreads();                             // ERf reads done; reuse smem

    // ---- tail: 4-way kp reduction. red reuses erf4 region (48 KB).
    float* red = (float*)smem;                   // [3kp'][2isub][8f][4r][64]
    if (kp && m == 0) {
        #pragma unroll
        for (int hh = 0; hh < NH; ++hh)
            #pragma unroll
            for (int r = 0; r < 4; ++r)
                sred[(((kp - 1) * 2 + isub) * 16 + hh * 4 + r) * 4 + quad] = sacc[hh][r];
    }
    float v[8][4], inv[4][4];
    #pragma unroll
    for (int hh = 0; hh < NH; ++hh) {
        if (kp) {
            #pragma unroll
            for (int f = 0; f < 8; ++f)
                #pragma unroll
                for (int r = 0; r < 4; ++r)
                    red[((((kp - 1) * 2 + isub) * 8 + f) * 4 + r) * 64 + lane] = acc[f][hh][r];
        }
        __syncthreads();
        if (kp == 0) {
            if (hh == 0) {
                #pragma unroll
                for (int h2 = 0; h2 < NH; ++h2)
                    #pragma unroll
                    for (int r = 0; r < 4; ++r) {
                        float S = sacc[h2][r];
                        #pragma unroll
                        for (int k2 = 0; k2 < 3; ++k2)
                            S += sred[((k2 * 2 + isub) * 16 + h2 * 4 + r) * 4 + quad];
                        inv[h2][r] = (S > 0.f) ? 1.f / S : 0.f;
                    }
            }
            #pragma unroll
            for (int f = 0; f < 8; ++f)
                #pragma unroll
                for (int r = 0; r < 4; ++r) {
                    float tot = acc[f][hh][r];
                    #pragma unroll
                    for (int k2 = 0; k2 < 3; ++k2)
                        tot += red[(((k2 * 2 + isub) * 8 + f) * 4 + r) * 64 + lane];
                    float t2 = tot * inv[hh][r];
                    if (hh == 0) v[f][r] = t2; else v[f][r] += t2;
                }
        }
        __syncthreads();
    }
    if (kp == 0) {
        #pragma unroll
        for (int r = 0; r < 4; ++r) {
            int orow = i0 + isub * 16 + quad * 4 + r;
            #pragma unroll
            for (int f = 0; f < 8; ++f)
                out[((size_t)b * NN + orow) * FOUT + f * 16 + m] =
                    fmaxf(0.25f * v[f][r], 0.f);
        }
    }
}

extern "C" void kernel_launch(void* const* d_in, const int* in_sizes, int n_in,
                              void* d_out, int out_size, void* d_ws, size_t ws_size,
                              hipStream_t stream) {
    const float* h    = (const float*)d_in[0];
    const int* adj    = (const int*)d_in[1];
    const float* Ww   = (const float*)d_in[2];
    const float* Wb   = (const float*)d_in[3];
    const float* attw = (const float*)d_in[4];
    float* out = (float*)d_out;
    char* ws = (char*)d_ws;
    // workspace layout (~3.3 MB)
    unsigned short* Whi = (unsigned short*)(ws);                 // 64 KB
    unsigned short* Wlo = (unsigned short*)(ws + 65536);         // 64 KB
    unsigned short* WhT = (unsigned short*)(ws + 131072);        // 2 MB [b][o][n] bf16
    float2*       ELpair = (float2*)(ws + 2228224);              // 256 KB [bh][i]
    float2*       ERf    = (float2*)(ws + 2490368);              // 256 KB [b][j][h] f32 pair
    u64*          mask   = (u64*)(ws + 2752512);                 // 512 KB

    k0_prep<<<dim3(128), dim3(256), 0, stream>>>(Ww, Whi, Wlo);
    k1_wh<<<dim3(BB * NN / 16 + NN), dim3(256), 0, stream>>>(h, Whi, Wlo, Wb, attw,
                                                             WhT, ELpair, ERf,
                                                             adj, mask);
    k2_reg<<<dim3(NN / 32, BB), dim3(512), 0, stream>>>(WhT, ERf, ELpair,
                                                        mask, out);
}